// Round 3
// baseline (637.287 us; speedup 1.0000x reference)
//
#include <hip/hip_runtime.h>
#include <math.h>

#define NCH   14595
#define WROW  14596          // row stride (floats) in transposed workspace (16B-aligned rows)
#define HR_C  13
#define IMG_H 512
#define IMG_W 512
#define BS    4

// param layout per lr-pixel: [bias|W] per layer, starts:
// L0:0 (1920), L1:1920 (4160), L2:6080 (4160), L3:10240 (4160), L4:14400 (195)

__global__ __launch_bounds__(256) void transpose_params(const float* __restrict__ lp,
                                                        float* __restrict__ wsT) {
    // lp: [BS][NCH][1024] -> wsT: [BS][1024][WROW]
    __shared__ float tile[64][65];
    int bid = blockIdx.x;
    int pt = bid & 15;
    int t  = bid >> 4;
    int ct = t % 229;
    int b  = t / 229;
    int c0 = ct * 64, p0 = pt * 64;
    int tp = threadIdx.x & 63;
    int tr = threadIdx.x >> 6;
#pragma unroll
    for (int s = 0; s < 16; s++) {
        int c = c0 + tr + s * 4;
        if (c < NCH)
            tile[tr + s * 4][tp] = lp[((size_t)b * NCH + c) * 1024 + p0 + tp];
    }
    __syncthreads();
#pragma unroll
    for (int s = 0; s < 16; s++) {
        int p = p0 + tr + s * 4;
        int c = c0 + tp;
        if (c < NCH)
            wsT[((size_t)b * 1024 + p) * WROW + c] = tile[tp][tr + s * 4];
    }
}

// Barrier that orders LDS only — does NOT drain vmcnt, so in-flight global
// (weight) loads survive across it.
__device__ __forceinline__ void block_sync_lds() {
    __builtin_amdgcn_sched_barrier(0);
    asm volatile("s_waitcnt lgkmcnt(0)" ::: "memory");
    __builtin_amdgcn_s_barrier();
    __builtin_amdgcn_sched_barrier(0);
}

// One hidden layer: act from LDS, weights streamed from global (L1-cached,
// wave-broadcast addresses, vmcnt queue independent of LDS lgkmcnt).
template<int NCI, bool USE_WS>
__device__ __forceinline__ void mlp_layer(const float* __restrict__ actT,
                                          const float* __restrict__ wrow,   // wsT row @ layer base
                                          const float* __restrict__ lp_col, // fallback: lp + b*NCH*1024 + pix
                                          int loff,
                                          int px0, int o0, float acc[4][8]) {
    if (USE_WS) {
        float4 b0 = *(const float4*)&wrow[o0];
        float4 b1 = *(const float4*)&wrow[o0 + 4];
#pragma unroll
        for (int i = 0; i < 4; i++) {
            acc[i][0] = b0.x; acc[i][1] = b0.y; acc[i][2] = b0.z; acc[i][3] = b0.w;
            acc[i][4] = b1.x; acc[i][5] = b1.y; acc[i][6] = b1.z; acc[i][7] = b1.w;
        }
    } else {
#pragma unroll
        for (int j = 0; j < 8; j++) {
            float bv = lp_col[(size_t)(loff + o0 + j) << 10];
#pragma unroll
            for (int i = 0; i < 4; i++) acc[i][j] = bv;
        }
    }
#pragma unroll 4
    for (int k = 0; k < NCI; k++) {
        float4 a = *(const float4*)&actT[k * 128 + px0];
        float4 w0, w1;
        if (USE_WS) {
            w0 = *(const float4*)&wrow[64 + (k << 6) + o0];
            w1 = *(const float4*)&wrow[64 + (k << 6) + o0 + 4];
        } else {
            int e = loff + 64 + (k << 6) + o0;
            w0.x = lp_col[(size_t)(e + 0) << 10]; w0.y = lp_col[(size_t)(e + 1) << 10];
            w0.z = lp_col[(size_t)(e + 2) << 10]; w0.w = lp_col[(size_t)(e + 3) << 10];
            w1.x = lp_col[(size_t)(e + 4) << 10]; w1.y = lp_col[(size_t)(e + 5) << 10];
            w1.z = lp_col[(size_t)(e + 6) << 10]; w1.w = lp_col[(size_t)(e + 7) << 10];
        }
#pragma unroll
        for (int i = 0; i < 4; i++) {
            float av = (i == 0) ? a.x : (i == 1) ? a.y : (i == 2) ? a.z : a.w;
            acc[i][0] = fmaf(av, w0.x, acc[i][0]);
            acc[i][1] = fmaf(av, w0.y, acc[i][1]);
            acc[i][2] = fmaf(av, w0.z, acc[i][2]);
            acc[i][3] = fmaf(av, w0.w, acc[i][3]);
            acc[i][4] = fmaf(av, w1.x, acc[i][4]);
            acc[i][5] = fmaf(av, w1.y, acc[i][5]);
            acc[i][6] = fmaf(av, w1.z, acc[i][6]);
            acc[i][7] = fmaf(av, w1.w, acc[i][7]);
        }
    }
}

template<bool USE_WS>
__global__ __launch_bounds__(256, 4) void asap_main(const float* __restrict__ hr,
                                                    const float* __restrict__ lp,
                                                    const float* __restrict__ wsT,
                                                    float* __restrict__ out) {
    __shared__ __align__(16) float actT[64 * 128];   // [ch][px] fp32, 32 KB — only LDS use

    // XCD-chunked swizzle (8192 blocks, 1024 per XCD, bijective)
    int bid0 = blockIdx.x;
    int bid  = ((bid0 & 7) << 10) | (bid0 >> 3);

    int half = bid & 1;
    int x    = (bid >> 1) & 31;
    int y    = (bid >> 6) & 31;
    int b    = bid >> 11;
    int tid  = threadIdx.x;
    int pix  = y * 32 + x;

    const float* wrow   = wsT + ((size_t)b * 1024 + pix) * WROW;
    const float* lp_col = lp + (size_t)b * NCH * 1024 + pix;

    // ---- build inputs: hr channels + cosine coords ----
    {
        int Y0 = y * 16 + half * 8, X0 = x * 16;
        for (int t = tid; t < HR_C * 128; t += 256) {
            int c = t >> 7, p = t & 127;
            int row = p >> 4, kx = p & 15;
            actT[c * 128 + p] =
                hr[(((size_t)b * HR_C + c) * IMG_H + Y0 + row) * IMG_W + X0 + kx];
        }
        if (tid < 128) {
            int p = tid, row = p >> 4, kx = p & 15;
            int kyg = half * 8 + row;
            const float two_pi = 6.28318530717958647692f;
            int f = 16;
#pragma unroll
            for (int fi = 0; fi < 4; fi++) {
                float ax = two_pi * (float)(kx & (f - 1)) / (float)f;
                float ay = two_pi * (float)(kyg & (f - 1)) / (float)f;
                actT[(13 + 4 * fi + 0) * 128 + p] = cosf(ax);
                actT[(13 + 4 * fi + 1) * 128 + p] = sinf(ax);
                actT[(13 + 4 * fi + 2) * 128 + p] = cosf(ay);
                actT[(13 + 4 * fi + 3) * 128 + p] = sinf(ay);
                f >>= 1;
            }
        }
    }
    block_sync_lds();

    int pg = tid & 31, og = tid >> 5;
    int px0 = pg << 2, o0 = og << 3;
    float acc[4][8];

    auto writeback = [&]() {
#pragma unroll
        for (int j = 0; j < 8; j++) {
            float4 v;
            v.x = acc[0][j]; v.y = acc[1][j]; v.z = acc[2][j]; v.w = acc[3][j];
            v.x = fmaxf(v.x, 0.01f * v.x);
            v.y = fmaxf(v.y, 0.01f * v.y);
            v.z = fmaxf(v.z, 0.01f * v.z);
            v.w = fmaxf(v.w, 0.01f * v.w);
            *(float4*)&actT[(o0 + j) * 128 + px0] = v;
        }
    };

    // ---- hidden layers ----
    mlp_layer<29, USE_WS>(actT, wrow + 0,     lp_col, 0,     px0, o0, acc);
    block_sync_lds();
    writeback();
    block_sync_lds();

    mlp_layer<64, USE_WS>(actT, wrow + 1920,  lp_col, 1920,  px0, o0, acc);
    block_sync_lds();
    writeback();
    block_sync_lds();

    mlp_layer<64, USE_WS>(actT, wrow + 6080,  lp_col, 6080,  px0, o0, acc);
    block_sync_lds();
    writeback();
    block_sync_lds();

    mlp_layer<64, USE_WS>(actT, wrow + 10240, lp_col, 10240, px0, o0, acc);
    block_sync_lds();
    writeback();
    block_sync_lds();

    // ---- final layer: nci=64, nco=3, tanh ----
    if (tid < 128) {
        int p = tid;
        float s0, s1, s2;
        if (USE_WS) {
            s0 = wrow[14400]; s1 = wrow[14401]; s2 = wrow[14402];
        } else {
            s0 = lp_col[(size_t)14400 << 10];
            s1 = lp_col[(size_t)14401 << 10];
            s2 = lp_col[(size_t)14402 << 10];
        }
#pragma unroll 4
        for (int k = 0; k < 64; k++) {
            float a = actT[k * 128 + p];
            float w0, w1, w2;
            if (USE_WS) {
                w0 = wrow[14403 + k * 3 + 0];
                w1 = wrow[14403 + k * 3 + 1];
                w2 = wrow[14403 + k * 3 + 2];
            } else {
                w0 = lp_col[(size_t)(14403 + k * 3 + 0) << 10];
                w1 = lp_col[(size_t)(14403 + k * 3 + 1) << 10];
                w2 = lp_col[(size_t)(14403 + k * 3 + 2) << 10];
            }
            s0 = fmaf(a, w0, s0);
            s1 = fmaf(a, w1, s1);
            s2 = fmaf(a, w2, s2);
        }
        int row = p >> 4, kx = p & 15;
        int Y = y * 16 + half * 8 + row, X = x * 16 + kx;
        size_t base = ((size_t)b * 3) * IMG_H * IMG_W + (size_t)Y * IMG_W + X;
        out[base]                             = tanhf(s0);
        out[base + (size_t)IMG_H * IMG_W]     = tanhf(s1);
        out[base + (size_t)2 * IMG_H * IMG_W] = tanhf(s2);
    }
}

extern "C" void kernel_launch(void* const* d_in, const int* in_sizes, int n_in,
                              void* d_out, int out_size, void* d_ws, size_t ws_size,
                              hipStream_t stream) {
    const float* hr = (const float*)d_in[0];
    const float* lp = (const float*)d_in[1];
    float* out = (float*)d_out;
    float* wsT = (float*)d_ws;

    size_t need = (size_t)BS * 1024 * WROW * sizeof(float);
    if (ws_size >= need) {
        transpose_params<<<BS * 229 * 16, 256, 0, stream>>>(lp, wsT);
        asap_main<true><<<8192, 256, 0, stream>>>(hr, lp, wsT, out);
    } else {
        asap_main<false><<<8192, 256, 0, stream>>>(hr, lp, wsT, out);
    }
}

// Round 4
// 598.265 us; speedup vs baseline: 1.0652x; 1.0652x over previous
//
#include <hip/hip_runtime.h>
#include <math.h>

#define NCH   14595
#define WROW  14600          // row stride (floats), 32B-aligned rows for s_load_dwordx8
#define HR_C  13
#define IMG_H 512
#define IMG_W 512
#define BS    4

typedef float f32x8 __attribute__((ext_vector_type(8)));
typedef float f32x2 __attribute__((ext_vector_type(2)));

// param layout per lr-pixel: [bias|W] per layer, starts:
// L0:0 (1920), L1:1920 (4160), L2:6080 (4160), L3:10240 (4160), L4:14400 (195)
// all layer starts are 32B-aligned (x4 bytes), and WROW*4 % 32 == 0.

__global__ __launch_bounds__(256) void transpose_params(const float* __restrict__ lp,
                                                        float* __restrict__ wsT) {
    // lp: [BS][NCH][1024] -> wsT: [BS][1024][WROW]
    __shared__ float tile[64][65];
    int bid = blockIdx.x;
    int pt = bid & 15;
    int t  = bid >> 4;
    int ct = t % 229;
    int b  = t / 229;
    int c0 = ct * 64, p0 = pt * 64;
    int tp = threadIdx.x & 63;
    int tr = threadIdx.x >> 6;
#pragma unroll
    for (int s = 0; s < 16; s++) {
        int c = c0 + tr + s * 4;
        if (c < NCH)
            tile[tr + s * 4][tp] = lp[((size_t)b * NCH + c) * 1024 + p0 + tp];
    }
    __syncthreads();
#pragma unroll
    for (int s = 0; s < 16; s++) {
        int p = p0 + tr + s * 4;
        int c = c0 + tp;
        if (c < NCH)
            wsT[((size_t)b * 1024 + p) * WROW + c] = tile[tp][tr + s * 4];
    }
}

// LDS-only barrier: orders ds ops, never drains vmcnt.
__device__ __forceinline__ void block_sync_lds() {
    __builtin_amdgcn_sched_barrier(0);
    asm volatile("s_waitcnt lgkmcnt(0)" ::: "memory");
    __builtin_amdgcn_s_barrier();
    __builtin_amdgcn_sched_barrier(0);
}

// One hidden layer. Wave owns 8 out channels for all 128 px; lane owns 2 px.
// wl = (per-wave) pointer at [bias(o0..o0+7) ...]; weights for (k, o0+j) at
// wl[64 + 64k + j]. Uniform address -> scalar loads on the SMEM pipe.
template<int NCI, bool USE_WS>
__device__ __forceinline__ void mlp_layer(const float* __restrict__ actT,
                                          const float* __restrict__ wl,
                                          const float* __restrict__ lp_col,
                                          int loff, int o0,
                                          int px0, float acc[2][8]) {
#pragma unroll
    for (int j = 0; j < 8; j++) {
        float bv = USE_WS ? wl[j] : lp_col[(size_t)(loff + o0 + j) << 10];
        acc[0][j] = bv; acc[1][j] = bv;
    }
#pragma unroll 4
    for (int k = 0; k < NCI; k++) {
        f32x2 a = *(const f32x2*)&actT[k * 128 + px0];
        if (USE_WS) {
            f32x8 w = *(const f32x8*)(wl + 64 + (k << 6));
#pragma unroll
            for (int j = 0; j < 8; j++) {
                acc[0][j] = fmaf(a.x, w[j], acc[0][j]);
                acc[1][j] = fmaf(a.y, w[j], acc[1][j]);
            }
        } else {
#pragma unroll
            for (int j = 0; j < 8; j++) {
                float w = lp_col[(size_t)(loff + 64 + (k << 6) + o0 + j) << 10];
                acc[0][j] = fmaf(a.x, w, acc[0][j]);
                acc[1][j] = fmaf(a.y, w, acc[1][j]);
            }
        }
    }
}

template<bool USE_WS>
__global__ __launch_bounds__(512, 8) void asap_main(const float* __restrict__ hr,
                                                    const float* __restrict__ lp,
                                                    const float* __restrict__ wsT,
                                                    float* __restrict__ out) {
    __shared__ __align__(16) float actT[64 * 128];   // 32 KB, only LDS use

    // XCD-chunked swizzle (8192 blocks, 1024 per XCD, bijective)
    int bid0 = blockIdx.x;
    int bid  = ((bid0 & 7) << 10) | (bid0 >> 3);

    int half = bid & 1;
    int x    = (bid >> 1) & 31;
    int y    = (bid >> 6) & 31;
    int b    = bid >> 11;
    int tid  = threadIdx.x;
    int lane = tid & 63;
    int wv   = __builtin_amdgcn_readfirstlane(tid >> 6);   // wave id 0..7, SGPR
    int pix  = y * 32 + x;

    const float* wrow   = wsT + ((size_t)b * 1024 + pix) * WROW;
    const float* lp_col = lp + (size_t)b * NCH * 1024 + pix;

    // ---- build inputs: hr channels + cosine coords ----
    {
        int Y0 = y * 16 + half * 8, X0 = x * 16;
        for (int t = tid; t < HR_C * 128; t += 512) {
            int c = t >> 7, p = t & 127;
            int row = p >> 4, kx = p & 15;
            actT[c * 128 + p] =
                hr[(((size_t)b * HR_C + c) * IMG_H + Y0 + row) * IMG_W + X0 + kx];
        }
        if (tid < 128) {
            int p = tid, row = p >> 4, kx = p & 15;
            int kyg = half * 8 + row;
            const float two_pi = 6.28318530717958647692f;
            int f = 16;
#pragma unroll
            for (int fi = 0; fi < 4; fi++) {
                float ax = two_pi * (float)(kx & (f - 1)) / (float)f;
                float ay = two_pi * (float)(kyg & (f - 1)) / (float)f;
                actT[(13 + 4 * fi + 0) * 128 + p] = cosf(ax);
                actT[(13 + 4 * fi + 1) * 128 + p] = sinf(ax);
                actT[(13 + 4 * fi + 2) * 128 + p] = cosf(ay);
                actT[(13 + 4 * fi + 3) * 128 + p] = sinf(ay);
                f >>= 1;
            }
        }
    }
    block_sync_lds();

    int o0  = wv << 3;
    int px0 = lane << 1;
    float acc[2][8];

    auto writeback = [&]() {
#pragma unroll
        for (int j = 0; j < 8; j++) {
            f32x2 v;
            v.x = fmaxf(acc[0][j], 0.01f * acc[0][j]);
            v.y = fmaxf(acc[1][j], 0.01f * acc[1][j]);
            *(f32x2*)&actT[(o0 + j) * 128 + px0] = v;
        }
    };

    const float* wl0 = wrow + 0     + o0;
    const float* wl1 = wrow + 1920  + o0;
    const float* wl2 = wrow + 6080  + o0;
    const float* wl3 = wrow + 10240 + o0;

    mlp_layer<29, USE_WS>(actT, wl0, lp_col, 0,     o0, px0, acc);
    block_sync_lds();
    writeback();
    block_sync_lds();

    mlp_layer<64, USE_WS>(actT, wl1, lp_col, 1920,  o0, px0, acc);
    block_sync_lds();
    writeback();
    block_sync_lds();

    mlp_layer<64, USE_WS>(actT, wl2, lp_col, 6080,  o0, px0, acc);
    block_sync_lds();
    writeback();
    block_sync_lds();

    mlp_layer<64, USE_WS>(actT, wl3, lp_col, 10240, o0, px0, acc);
    block_sync_lds();
    writeback();
    block_sync_lds();

    // ---- final layer: nci=64, nco=3, tanh; waves 0..2 (one out channel each) ----
    if (wv < 3) {
        float sA, sB;
        if (USE_WS) {
            float bv = wrow[14400 + wv];
            sA = bv; sB = bv;
#pragma unroll 4
            for (int k = 0; k < 64; k++) {
                f32x2 a = *(const f32x2*)&actT[k * 128 + px0];
                float w = wrow[14403 + k * 3 + wv];
                sA = fmaf(a.x, w, sA);
                sB = fmaf(a.y, w, sB);
            }
        } else {
            float bv = lp_col[(size_t)(14400 + wv) << 10];
            sA = bv; sB = bv;
#pragma unroll 4
            for (int k = 0; k < 64; k++) {
                f32x2 a = *(const f32x2*)&actT[k * 128 + px0];
                float w = lp_col[(size_t)(14403 + k * 3 + wv) << 10];
                sA = fmaf(a.x, w, sA);
                sB = fmaf(a.y, w, sB);
            }
        }
        int row = px0 >> 4, kx = px0 & 15;
        int Y = y * 16 + half * 8 + row, X = x * 16 + kx;
        size_t base = ((size_t)(b * 3 + wv)) * IMG_H * IMG_W + (size_t)Y * IMG_W + X;
        f32x2 o;
        o.x = tanhf(sA);
        o.y = tanhf(sB);
        *(f32x2*)&out[base] = o;
    }
}

extern "C" void kernel_launch(void* const* d_in, const int* in_sizes, int n_in,
                              void* d_out, int out_size, void* d_ws, size_t ws_size,
                              hipStream_t stream) {
    const float* hr = (const float*)d_in[0];
    const float* lp = (const float*)d_in[1];
    float* out = (float*)d_out;
    float* wsT = (float*)d_ws;

    size_t need = (size_t)BS * 1024 * WROW * sizeof(float);
    if (ws_size >= need) {
        transpose_params<<<BS * 229 * 16, 256, 0, stream>>>(lp, wsT);
        asap_main<true><<<8192, 512, 0, stream>>>(hr, lp, wsT, out);
    } else {
        asap_main<false><<<8192, 512, 0, stream>>>(hr, lp, wsT, out);
    }
}